// Round 2
// baseline (307.759 us; speedup 1.0000x reference)
//
#include <hip/hip_runtime.h>

#define S_LEN 8192
#define DIM   64
#define WIN   64
#define QB    32          // queries per block
#define CHUNK 80          // key rows staged per chunk
#define NCHUNK 2
#define ROWS_PER_WAVE 20  // CHUNK / 4 waves
#define CSTRIDE 68        // combine-buffer row stride (64 o + 1 l + pad)

__global__ __launch_bounds__(256, 2)
void swa_fwd(const float* __restrict__ qg,
             const float* __restrict__ kg,
             const float* __restrict__ vg,
             float* __restrict__ outg, int B) {
    __shared__ float smem[2 * CHUNK * DIM];   // 40 KiB: ks | vs, reused as combine buf
    float* ks = smem;
    float* vs = smem + CHUNK * DIM;

    const int tid  = threadIdx.x;
    const int wave = tid >> 6;
    const int lane = tid & 63;
    const int grp  = lane >> 3;   // 8 groups per wave
    const int sub  = lane & 7;    // dim slice: 8*sub .. 8*sub+7

    const int nqb = S_LEN / QB;   // 256 query-blocks per batch
    const int b   = blockIdx.x / nqb;
    const int s0  = (blockIdx.x % nqb) * QB;

    // Each 8-lane group owns 4 queries: s0 + 4*grp + jj.
    // Pre-scale q by D^-0.5 * log2(e) so score exp is a single exp2f.
    const float qscale = 0.125f * 1.44269504088896340736f;
    float qreg[4][8];
    int   vlo[4], vhi[4];
    #pragma unroll
    for (int jj = 0; jj < 4; ++jj) {
        int s = s0 + 4 * grp + jj;
        vlo[jj] = (s - WIN < 0) ? 0 : (s - WIN);
        vhi[jj] = (s + WIN > S_LEN - 1) ? (S_LEN - 1) : (s + WIN);
        const float4* qp = reinterpret_cast<const float4*>(qg + (b * S_LEN + s) * DIM + 8 * sub);
        float4 a = qp[0], c = qp[1];
        qreg[jj][0] = a.x * qscale; qreg[jj][1] = a.y * qscale;
        qreg[jj][2] = a.z * qscale; qreg[jj][3] = a.w * qscale;
        qreg[jj][4] = c.x * qscale; qreg[jj][5] = c.y * qscale;
        qreg[jj][6] = c.z * qscale; qreg[jj][7] = c.w * qscale;
    }

    float l[4] = {0.f, 0.f, 0.f, 0.f};
    float o[4][8] = {};

    for (int ch = 0; ch < NCHUNK; ++ch) {
        const int c0 = s0 - WIN + ch * CHUNK;
        __syncthreads();   // protect LDS from previous chunk's readers
        // ---- stage K/V chunk: 1280 float4 per tensor, 5 per thread, coalesced
        #pragma unroll
        for (int t = 0; t < 5; ++t) {
            int f4  = tid + t * 256;
            int row = f4 >> 4;
            int col = (f4 & 15) << 2;
            int gr  = c0 + row;
            float4 kv = make_float4(0.f, 0.f, 0.f, 0.f);
            float4 vv = kv;
            if (gr >= 0 && gr < S_LEN) {
                int base = (b * S_LEN + gr) * DIM + col;
                kv = *reinterpret_cast<const float4*>(kg + base);
                vv = *reinterpret_cast<const float4*>(vg + base);
            }
            reinterpret_cast<float4*>(ks)[f4] = kv;
            reinterpret_cast<float4*>(vs)[f4] = vv;
        }
        __syncthreads();

        // ---- each wave processes its 20 rows of the chunk (key-split)
        const int lbase = wave * ROWS_PER_WAVE;
        for (int rr = 0; rr < ROWS_PER_WAVE; ++rr) {
            const int lrow = lbase + rr;
            const int r    = c0 + lrow;
            const float4* kp = reinterpret_cast<const float4*>(ks + lrow * DIM + 8 * sub);
            float4 k0 = kp[0], k1 = kp[1];
            const float4* vp = reinterpret_cast<const float4*>(vs + lrow * DIM + 8 * sub);
            float4 v0 = vp[0], v1 = vp[1];

            float p[4];
            #pragma unroll
            for (int jj = 0; jj < 4; ++jj) {
                float pa = qreg[jj][0]*k0.x + qreg[jj][1]*k0.y + qreg[jj][2]*k0.z + qreg[jj][3]*k0.w;
                float pb = qreg[jj][4]*k1.x + qreg[jj][5]*k1.y + qreg[jj][6]*k1.z + qreg[jj][7]*k1.w;
                p[jj] = pa + pb;
            }
            // reduce partial dot across the 8 sublanes of the group
            #pragma unroll
            for (int off = 4; off; off >>= 1) {
                #pragma unroll
                for (int jj = 0; jj < 4; ++jj)
                    p[jj] += __shfl_xor(p[jj], off, 8);
            }
            #pragma unroll
            for (int jj = 0; jj < 4; ++jj) {
                bool valid = (r >= vlo[jj]) && (r <= vhi[jj]);
                float e = valid ? exp2f(p[jj]) : 0.0f;
                l[jj] += e;
                o[jj][0] += e * v0.x; o[jj][1] += e * v0.y;
                o[jj][2] += e * v0.z; o[jj][3] += e * v0.w;
                o[jj][4] += e * v1.x; o[jj][5] += e * v1.y;
                o[jj][6] += e * v1.z; o[jj][7] += e * v1.w;
            }
        }
    }
    __syncthreads();   // all waves done computing; LDS reusable

    // ---- write per-wave partials (no max shift used -> partials just sum)
    float* comb = smem;   // [4 waves][32 q][CSTRIDE]
    #pragma unroll
    for (int jj = 0; jj < 4; ++jj) {
        int qi = 4 * grp + jj;
        float* dst = comb + (wave * QB + qi) * CSTRIDE + 8 * sub;
        #pragma unroll
        for (int e = 0; e < 8; ++e) dst[e] = o[jj][e];
        if (sub == 0) comb[(wave * QB + qi) * CSTRIDE + 64] = l[jj];
    }
    __syncthreads();

    // ---- combine across 4 waves and store: thread t -> query t>>3, dims (t&7)*8..
    {
        int qi = tid >> 3;
        int ds = (tid & 7) * 8;
        float acc[8] = {};
        float denom = 0.f;
        #pragma unroll
        for (int w = 0; w < 4; ++w) {
            const float* src = comb + (w * QB + qi) * CSTRIDE;
            denom += src[64];
            #pragma unroll
            for (int e = 0; e < 8; ++e) acc[e] += src[ds + e];
        }
        float inv = 1.0f / denom;
        float* op = outg + (b * S_LEN + s0 + qi) * DIM + ds;
        #pragma unroll
        for (int e = 0; e < 8; ++e) op[e] = acc[e] * inv;
    }
}

extern "C" void kernel_launch(void* const* d_in, const int* in_sizes, int n_in,
                              void* d_out, int out_size, void* d_ws, size_t ws_size,
                              hipStream_t stream) {
    const float* q = (const float*)d_in[0];
    const float* k = (const float*)d_in[1];
    const float* v = (const float*)d_in[2];
    float* out = (float*)d_out;
    int B = in_sizes[0] / (S_LEN * DIM);
    dim3 grid(B * (S_LEN / QB));
    swa_fwd<<<grid, 256, 0, stream>>>(q, k, v, out, B);
}

// Round 3
// 84.607 us; speedup vs baseline: 3.6375x; 3.6375x over previous
//
#include <hip/hip_runtime.h>

#define S_LEN 8192
#define DIM   64
#define WIN   64
#define QB    32            // queries per block (4 waves x 8 queries)
#define ROWS  160           // QB + 2*WIN rows staged
#define JCOUNT 136          // rows per wave: 8 + 2*WIN
#define NXCD  8

// Butterfly add over 8-lane groups, pure VALU (DPP), no DS pipe.
// ctrl: 0xB1 = quad_perm(1,0,3,2) -> xor1; 0x4E = quad_perm(2,3,0,1) -> xor2;
//       0x141 = row_half_mirror  -> xor7 (crosses quads within the octet)
template<int CTRL>
__device__ __forceinline__ float dpp_add(float v) {
    int s = __builtin_amdgcn_update_dpp(0, __float_as_int(v), CTRL, 0xF, 0xF, true);
    return v + __int_as_float(s);
}

__global__ __launch_bounds__(256, 2)
void swa_fwd(const float* __restrict__ qg,
             const float* __restrict__ kg,
             const float* __restrict__ vg,
             float* __restrict__ outg) {
    __shared__ float smem[2 * ROWS * DIM];   // 80 KiB exactly -> 2 blocks/CU
    float* ks = smem;
    float* vs = smem + ROWS * DIM;

    // XCD-aware swizzle: consecutive LOGICAL blocks (which share window rows)
    // land on the same XCD's L2. gridDim.x is a multiple of 8 -> bijective.
    const int nwg = gridDim.x;
    const int cpx = nwg / NXCD;
    const int lb  = (blockIdx.x % NXCD) * cpx + blockIdx.x / NXCD;

    const int nqb = S_LEN / QB;          // 256 query-blocks per batch
    const int b   = lb / nqb;
    const int s0  = (lb % nqb) * QB;

    const int tid = threadIdx.x;
    const int c0  = s0 - WIN;            // first staged row (may be <0)

    // ---- stage K/V rows [s0-64, s0+96): 2560 float4 each, 10 per thread,
    // coalesced 4KB per instruction; OOB rows zero-filled (avoids NaN poison).
    for (int t = 0; t < 10; ++t) {
        int f4  = tid + t * 256;         // 0..2559
        int gr  = c0 + (f4 >> 4);
        float4 kv = make_float4(0.f, 0.f, 0.f, 0.f);
        float4 vv = kv;
        if ((unsigned)gr < (unsigned)S_LEN) {
            int base = (b * S_LEN + gr) * DIM + ((f4 & 15) << 2);
            kv = *reinterpret_cast<const float4*>(kg + base);
            vv = *reinterpret_cast<const float4*>(vg + base);
        }
        reinterpret_cast<float4*>(ks)[f4] = kv;
        reinterpret_cast<float4*>(vs)[f4] = vv;
    }

    const int wv   = tid >> 6;           // wave 0..3 -> owns queries s0+8*wv..+7
    const int lane = tid & 63;
    const int g    = lane >> 3;          // group 0..7 -> one query
    const int sub  = lane & 7;           // dim slice 8*sub..8*sub+7

    const int q = s0 + 8 * wv + g;

    // q fragment, pre-scaled by D^-0.5 * log2(e) so score->prob is one exp2
    const float qscale = 0.125f * 1.44269504088896340736f;
    const float* qp = qg + (b * S_LEN + q) * DIM + 8 * sub;
    float4 q0 = *reinterpret_cast<const float4*>(qp);
    float4 q1 = *reinterpret_cast<const float4*>(qp + 4);
    q0.x *= qscale; q0.y *= qscale; q0.z *= qscale; q0.w *= qscale;
    q1.x *= qscale; q1.y *= qscale; q1.z *= qscale; q1.w *= qscale;

    // valid j range for this query: r(j) = c0 + 8*wv + j must lie in
    // [q-WIN, q+WIN] ∩ [0, S-1]
    const int jlo = max(g, WIN - s0 - 8 * wv);
    const int jhi = min(g + 2 * WIN, S_LEN - 1 - s0 + WIN - 8 * wv);

    __syncthreads();

    const float* kbase = ks + (8 * wv) * DIM + 8 * sub;
    const float* vbase = vs + (8 * wv) * DIM + 8 * sub;

    float l = 0.f;
    float o[8] = {0.f, 0.f, 0.f, 0.f, 0.f, 0.f, 0.f, 0.f};

    #pragma unroll 4
    for (int j = 0; j < JCOUNT; ++j) {
        const float* kr = kbase + j * DIM;
        const float* vr = vbase + j * DIM;
        float4 k0 = *reinterpret_cast<const float4*>(kr);
        float4 k1 = *reinterpret_cast<const float4*>(kr + 4);
        float4 v0 = *reinterpret_cast<const float4*>(vr);
        float4 v1 = *reinterpret_cast<const float4*>(vr + 4);

        float p = q0.x * k0.x + q0.y * k0.y + q0.z * k0.z + q0.w * k0.w
                + q1.x * k1.x + q1.y * k1.y + q1.z * k1.z + q1.w * k1.w;
        p = dpp_add<0xB1>(p);     // xor1
        p = dpp_add<0x4E>(p);     // xor2
        p = dpp_add<0x141>(p);    // xor7 (half-mirror) -> full 8-lane sum

        float e = (j >= jlo && j <= jhi) ? exp2f(p) : 0.f;
        l += e;
        o[0] += e * v0.x; o[1] += e * v0.y; o[2] += e * v0.z; o[3] += e * v0.w;
        o[4] += e * v1.x; o[5] += e * v1.y; o[6] += e * v1.z; o[7] += e * v1.w;
    }

    const float inv = 1.0f / l;
    float* op = outg + (b * S_LEN + q) * DIM + 8 * sub;
    float4 r0 = make_float4(o[0] * inv, o[1] * inv, o[2] * inv, o[3] * inv);
    float4 r1 = make_float4(o[4] * inv, o[5] * inv, o[6] * inv, o[7] * inv);
    *reinterpret_cast<float4*>(op)     = r0;
    *reinterpret_cast<float4*>(op + 4) = r1;
}

extern "C" void kernel_launch(void* const* d_in, const int* in_sizes, int n_in,
                              void* d_out, int out_size, void* d_ws, size_t ws_size,
                              hipStream_t stream) {
    const float* q = (const float*)d_in[0];
    const float* k = (const float*)d_in[1];
    const float* v = (const float*)d_in[2];
    float* out = (float*)d_out;
    int B = in_sizes[0] / (S_LEN * DIM);
    dim3 grid(B * (S_LEN / QB));          // 512 blocks for B=2
    swa_fwd<<<grid, 256, 0, stream>>>(q, k, v, out);
}